// Round 5
// baseline (166.440 us; speedup 1.0000x reference)
//
#include <hip/hip_runtime.h>

// Fused NCA step — wave = one full 512-px row, 8 px/lane.
// Circular pad in w via lane shuffles (row wraps exactly around the wave).
// Row bases wave-uniform -> SGPR. Column-separable stencil.
// __launch_bounds__(256, 4): R4 showed the compiler spilling acc[6][8] to
// scratch at VGPR=48 (FETCH/WRITE inflated by ~42MB of scratch traffic).
// Requesting 4 waves/EU raises the reg ceiling to 128 — peak liveness ~90
// fits with zero spill while keeping 16 waves/CU.

constexpr int Bn = 16, Cn = 4, Hn = 512, Wn = 512, HID = 6;

__device__ __forceinline__ float frcp(float v) { return __builtin_amdgcn_rcpf(v); }

__global__ __launch_bounds__(256, 4) void nca_row2(
    const float* __restrict__ x,
    const float* __restrict__ w1w, const float* __restrict__ w1b,
    const float* __restrict__ w2w, const float* __restrict__ w2b,
    const float* __restrict__ w3w, const float* __restrict__ w3b,
    float* __restrict__ out)
{
    const int lane = threadIdx.x & 63;
    const int wv   = threadIdx.x >> 6;
    // wave-uniform row id 0..8191 — force into SGPR so row bases are scalar
    const int row = __builtin_amdgcn_readfirstlane((int)blockIdx.x * 4 + wv);
    const int h  = row & (Hn - 1);
    const int b  = row >> 9;
    const int hm = (h - 1) & (Hn - 1);
    const int hp = (h + 1) & (Hn - 1);

    const int w0 = lane << 3;                    // 8 px per lane, full row per wave
    const int laneL = (lane + 63) & 63;
    const int laneR = (lane + 1) & 63;

    const size_t plane = (size_t)Hn * Wn;
    const float* xb = x + (size_t)b * Cn * plane;

    float acc[HID][8];
    #pragma unroll
    for (int o = 0; o < HID; ++o) {
        float bv = w1b[o];
        #pragma unroll
        for (int i = 0; i < 8; ++i) acc[o][i] = bv;
    }

    #pragma unroll
    for (int c = 0; c < Cn; ++c) {
        const float* rt = xb + c * plane + (size_t)hm * Wn;   // wave-uniform bases
        const float* rm = xb + c * plane + (size_t)h  * Wn;
        const float* rb = xb + c * plane + (size_t)hp * Wn;
        float4 t0 = *(const float4*)(rt + w0), t1 = *(const float4*)(rt + w0 + 4);
        float4 m0 = *(const float4*)(rm + w0), m1 = *(const float4*)(rm + w0 + 4);
        float4 b0 = *(const float4*)(rb + w0), b1 = *(const float4*)(rb + w0 + 4);

        // kill t/q immediately: only m, s, d stay live (24 regs/channel)
        float m[8] = { m0.x, m0.y, m0.z, m0.w, m1.x, m1.y, m1.z, m1.w };
        float s[8], d[8];
        {
            float t[8] = { t0.x, t0.y, t0.z, t0.w, t1.x, t1.y, t1.z, t1.w };
            float q[8] = { b0.x, b0.y, b0.z, b0.w, b1.x, b1.y, b1.z, b1.w };
            #pragma unroll
            for (int j = 0; j < 8; ++j) {
                s[j] = fmaf(2.f, m[j], t[j] + q[j]);   // vertical [1,2,1]
                d[j] = q[j] - t[j];                    // vertical [-1,0,1]
            }
        }

        // circular halos via wave shuffle: wave spans the whole row, wrap exact
        float sL = __shfl(s[7], laneL), dL = __shfl(d[7], laneL);
        float sR = __shfl(s[0], laneR), dR = __shfl(d[0], laneR);

        #pragma unroll
        for (int i = 0; i < 8; ++i) {
            float sm = (i == 0) ? sL : s[i - 1];
            float sp = (i == 7) ? sR : s[i + 1];
            float dm = (i == 0) ? dL : d[i - 1];
            float dp = (i == 7) ? dR : d[i + 1];
            float mc = m[i];
            float y1 = sp - sm;                                   // sobel_x
            float y2 = fmaf(2.f, d[i], dm + dp);                  // sobel_y
            float y3 = fmaf(-16.f, mc, fmaf(2.f, s[i], sm + sp)); // laplacian
            #pragma unroll
            for (int o = 0; o < HID; ++o) {
                acc[o][i] = fmaf(w1w[o*16 + c*4 + 0], mc,
                            fmaf(w1w[o*16 + c*4 + 1], y1,
                            fmaf(w1w[o*16 + c*4 + 2], y2,
                            fmaf(w1w[o*16 + c*4 + 3], y3, acc[o][i]))));
            }
        }
    }

    #pragma unroll
    for (int o = 0; o < HID; ++o)
        #pragma unroll
        for (int i = 0; i < 8; ++i)
            acc[o][i] = fmaxf(acc[o][i], 0.f);   // relu

    // epilogue: per output channel, reload x centers (L2-hot) and blend
    float* ob = out + (size_t)b * Cn * plane + (size_t)h * Wn;
    #pragma unroll
    for (int j = 0; j < Cn; ++j) {
        const float* rc = xb + j * plane + (size_t)h * Wn;
        float4 c0 = *(const float4*)(rc + w0), c1 = *(const float4*)(rc + w0 + 4);
        float xc[8] = { c0.x, c0.y, c0.z, c0.w, c1.x, c1.y, c1.z, c1.w };
        float res[8];
        #pragma unroll
        for (int i = 0; i < 8; ++i) {
            float u = w2b[j], gg = w3b[j];
            #pragma unroll
            for (int o = 0; o < HID; ++o) {
                u  = fmaf(w2w[j*HID + o], acc[o][i], u);
                gg = fmaf(w3w[j*HID + o], acc[o][i], gg);
            }
            // tanh(u) = 1 - 2/(exp(2u)+1); sigmoid(g) = 1/(1+exp(-g))
            float th = 1.f - 2.f * frcp(__expf(2.f * u) + 1.f);
            float sg = frcp(1.f + __expf(-gg));
            res[i] = fmaf(sg, xc[i] - th, th);
        }
        *(float4*)(ob + j * plane + w0)     = make_float4(res[0], res[1], res[2], res[3]);
        *(float4*)(ob + j * plane + w0 + 4) = make_float4(res[4], res[5], res[6], res[7]);
    }
}

extern "C" void kernel_launch(void* const* d_in, const int* in_sizes, int n_in,
                              void* d_out, int out_size, void* d_ws, size_t ws_size,
                              hipStream_t stream) {
    const float* x   = (const float*)d_in[0];
    // d_in[1] = filters — fixed identity/sobel/laplacian stack, hardcoded above
    const float* w1w = (const float*)d_in[2];
    const float* w1b = (const float*)d_in[3];
    const float* w2w = (const float*)d_in[4];
    const float* w2b = (const float*)d_in[5];
    const float* w3w = (const float*)d_in[6];
    const float* w3b = (const float*)d_in[7];
    float* out = (float*)d_out;

    int rows   = Bn * Hn;                        // 8192 waves, one row each
    int blocks = rows / 4;                       // 2048 blocks of 4 waves
    nca_row2<<<blocks, 256, 0, stream>>>(x, w1w, w1b, w2w, w2b, w3w, w3b, out);
}

// Round 6
// 133.564 us; speedup vs baseline: 1.2462x; 1.2462x over previous
//
#include <hip/hip_runtime.h>

// Fused NCA step — wave = half row (256 px), 4 px/lane.
// R1 (4px/lane, VGPR=68, no spill) is the frontier; R4/R5 showed 8px/lane's
// 48-reg accumulator forces scratch spills (FETCH 78->102MB). This keeps the
// live set ~R1-sized (acc[6][4]=24) and adds R4's structural wins:
//   - wave-uniform SGPR row bases (readfirstlane'd wave id)
//   - column-separable stencil: s=t+2m+b, d=b-t
//   - halos via lane shuffle; wave-edge lanes fixed by 3 masked scalar loads
// Loads/thread 36 -> 24, stencil ops/channel ~48 -> ~34.

constexpr int Bn = 16, Cn = 4, Hn = 512, Wn = 512, HID = 6;

__device__ __forceinline__ float frcp(float v) { return __builtin_amdgcn_rcpf(v); }

__global__ __launch_bounds__(256) void nca_half(
    const float* __restrict__ x,
    const float* __restrict__ w1w, const float* __restrict__ w1b,
    const float* __restrict__ w2w, const float* __restrict__ w2b,
    const float* __restrict__ w3w, const float* __restrict__ w3b,
    float* __restrict__ out)
{
    const int lane = threadIdx.x & 63;
    // wave id 0..16383, forced wave-uniform -> SGPR row bases
    const int wid = __builtin_amdgcn_readfirstlane((int)blockIdx.x * 4 + (threadIdx.x >> 6));
    const int half = wid & 1;                    // which half of the row
    const int h    = (wid >> 1) & (Hn - 1);
    const int b    = wid >> 10;
    const int hm = (h - 1) & (Hn - 1);
    const int hp = (h + 1) & (Hn - 1);

    const int W0 = half << 8;                    // 0 or 256
    const int w0 = W0 + (lane << 2);             // 4 px per lane

    // wave-edge halo columns (circular in w): lane 0 needs col W0-1, lane 63
    // needs col W0+256; one masked address serves both.
    const int colL = (W0 - 1) & (Wn - 1);
    const int colR = (W0 + 256) & (Wn - 1);
    const int colFix = (lane == 0) ? colL : colR;
    const int laneL = (lane + 63) & 63;
    const int laneR = (lane + 1) & 63;

    const size_t plane = (size_t)Hn * Wn;
    const float* xb = x + (size_t)b * Cn * plane;

    float acc[HID][4];
    #pragma unroll
    for (int o = 0; o < HID; ++o) {
        float bv = w1b[o];
        #pragma unroll
        for (int i = 0; i < 4; ++i) acc[o][i] = bv;
    }

    float xc[Cn][4];                             // center pixels for the blend

    #pragma unroll
    for (int c = 0; c < Cn; ++c) {
        const float* rt = xb + c * plane + (size_t)hm * Wn;   // SGPR bases
        const float* rm = xb + c * plane + (size_t)h  * Wn;
        const float* rb = xb + c * plane + (size_t)hp * Wn;
        float4 t4 = *(const float4*)(rt + w0);
        float4 m4 = *(const float4*)(rm + w0);
        float4 q4 = *(const float4*)(rb + w0);
        float tF = rt[colFix], mF = rm[colFix], qF = rb[colFix];  // edge fix

        float m[4] = { m4.x, m4.y, m4.z, m4.w };
        float s[4], d[4];
        {
            float t[4] = { t4.x, t4.y, t4.z, t4.w };
            float q[4] = { q4.x, q4.y, q4.z, q4.w };
            #pragma unroll
            for (int j = 0; j < 4; ++j) {
                s[j] = fmaf(2.f, m[j], t[j] + q[j]);   // vertical [1,2,1]
                d[j] = q[j] - t[j];                    // vertical [-1,0,1]
            }
        }
        float sF = fmaf(2.f, mF, tF + qF);
        float dF = qF - tF;

        // interior halos from neighbor lanes; edge lanes take the fix value
        float sL = __shfl(s[3], laneL), dL = __shfl(d[3], laneL);
        float sR = __shfl(s[0], laneR), dR = __shfl(d[0], laneR);
        sL = (lane == 0) ? sF : sL;  dL = (lane == 0) ? dF : dL;
        sR = (lane == 63) ? sF : sR; dR = (lane == 63) ? dF : dR;

        #pragma unroll
        for (int i = 0; i < 4; ++i) {
            float sm = (i == 0) ? sL : s[i - 1];
            float sp = (i == 3) ? sR : s[i + 1];
            float dm = (i == 0) ? dL : d[i - 1];
            float dp = (i == 3) ? dR : d[i + 1];
            float mc = m[i];
            float y1 = sp - sm;                                   // sobel_x
            float y2 = fmaf(2.f, d[i], dm + dp);                  // sobel_y
            float y3 = fmaf(-16.f, mc, fmaf(2.f, s[i], sm + sp)); // laplacian
            xc[c][i] = mc;
            #pragma unroll
            for (int o = 0; o < HID; ++o) {
                acc[o][i] = fmaf(w1w[o*16 + c*4 + 0], mc,
                            fmaf(w1w[o*16 + c*4 + 1], y1,
                            fmaf(w1w[o*16 + c*4 + 2], y2,
                            fmaf(w1w[o*16 + c*4 + 3], y3, acc[o][i]))));
            }
        }
    }

    #pragma unroll
    for (int o = 0; o < HID; ++o)
        #pragma unroll
        for (int i = 0; i < 4; ++i)
            acc[o][i] = fmaxf(acc[o][i], 0.f);   // relu

    float* ob = out + (size_t)b * Cn * plane + (size_t)h * Wn + w0;
    #pragma unroll
    for (int j = 0; j < Cn; ++j) {
        float res[4];
        #pragma unroll
        for (int i = 0; i < 4; ++i) {
            float u = w2b[j], gg = w3b[j];
            #pragma unroll
            for (int o = 0; o < HID; ++o) {
                u  = fmaf(w2w[j*HID + o], acc[o][i], u);
                gg = fmaf(w3w[j*HID + o], acc[o][i], gg);
            }
            // tanh(u) = 1 - 2/(exp(2u)+1); sigmoid(g) = 1/(1+exp(-g))
            float th = 1.f - 2.f * frcp(__expf(2.f * u) + 1.f);
            float sg = frcp(1.f + __expf(-gg));
            res[i] = fmaf(sg, xc[j][i] - th, th);
        }
        *(float4*)(ob + (size_t)j * plane) = make_float4(res[0], res[1], res[2], res[3]);
    }
}

extern "C" void kernel_launch(void* const* d_in, const int* in_sizes, int n_in,
                              void* d_out, int out_size, void* d_ws, size_t ws_size,
                              hipStream_t stream) {
    const float* x   = (const float*)d_in[0];
    // d_in[1] = filters — fixed identity/sobel/laplacian stack, hardcoded above
    const float* w1w = (const float*)d_in[2];
    const float* w1b = (const float*)d_in[3];
    const float* w2w = (const float*)d_in[4];
    const float* w2b = (const float*)d_in[5];
    const float* w3w = (const float*)d_in[6];
    const float* w3b = (const float*)d_in[7];
    float* out = (float*)d_out;

    int waves  = Bn * Hn * 2;                    // 16384 half-row waves
    int blocks = waves / 4;                      // 4096 blocks (4 waves each)
    nca_half<<<blocks, 256, 0, stream>>>(x, w1w, w1b, w2w, w2b, w3w, w3b, out);
}